// Round 7
// baseline (54.725 us; speedup 1.0000x reference)
//
#include <hip/hip_runtime.h>

typedef __attribute__((ext_vector_type(8))) short bf16x8;
typedef __attribute__((ext_vector_type(4))) float f32x4;

constexpr int TN = 8192;   // tokens
constexpr int DN = 4096;   // model dim
constexpr int EN = 64;     // experts

constexpr int BM  = 32;        // rows per block
constexpr int KC  = 128;       // k per staged chunk (4 K32 slots = 4 waves)
constexpr int NS  = DN / 32;   // 128 MFMA k-steps total
constexpr int KPB = KC + 8;    // A k-stride bf16 (272B row: odd quad stride -> uniform banks)

__device__ __forceinline__ unsigned short f2bf(float f) {  // RNE f32->bf16
    unsigned u = __builtin_bit_cast(unsigned, f);
    u += 0x7FFFu + ((u >> 16) & 1u);
    return (unsigned short)(u >> 16);
}
__device__ __forceinline__ float bf2f(unsigned short h) {
    unsigned u = ((unsigned)h) << 16;
    return __builtin_bit_cast(float, u);
}

// Kernel 0: split wg into hi/lo bf16 planes in MFMA-fragment order:
// BF[p][s][et][lane*8+j] = plane_p( wg[et*16+(lane&15)][s*32+(lane>>4)*8+j] )
// so a wave's B-fragment load in the GEMM is base + lane*16B (1KB coalesced).
__global__ __launch_bounds__(256)
void wg_frag_kernel(const float* __restrict__ wg, unsigned short* __restrict__ BF) {
    const int gid = blockIdx.x * 256 + threadIdx.x;  // 65536 items
    const int l  = gid & 63;
    const int et = (gid >> 6) & 3;
    const int s  = (gid >> 8) & (NS - 1);
    const int p  = gid >> 15;
    const int e  = et * 16 + (l & 15);
    const int k  = s * 32 + (l >> 4) * 8;

    const float* src = wg + (size_t)e * DN + k;
    float4 v0 = *reinterpret_cast<const float4*>(src);
    float4 v1 = *reinterpret_cast<const float4*>(src + 4);
    float f[8] = {v0.x, v0.y, v0.z, v0.w, v1.x, v1.y, v1.z, v1.w};
    unsigned short o[8];
#pragma unroll
    for (int j = 0; j < 8; ++j) {
        unsigned short h = f2bf(f[j]);
        o[j] = p ? f2bf(f[j] - bf2f(h)) : h;
    }
    unsigned short* dst = BF + (((size_t)p * NS + s) * 4 + et) * 512 + (size_t)l * 8;
    *reinterpret_cast<ushort4*>(dst)     = make_ushort4(o[0], o[1], o[2], o[3]);
    *reinterpret_cast<ushort4*>(dst + 4) = make_ushort4(o[4], o[5], o[6], o[7]);
}

// Kernel 1: split-bf16 MFMA GEMM partials. Grid = 256 row-tiles * 2 k-splits
// = 512 blocks (2/CU), 256 threads = 4 waves. Wave = K32 slot; each wave
// computes BOTH 16-row halves (B loaded once per 32 rows -> B L2 traffic
// halved vs BM=16). Depth-2 register x-prefetch; B prefetch issued FIRST
// each iteration so compute's B vmcnt-wait never forces fresh x loads.
template <int KSPLIT>
__global__ __launch_bounds__(256, 2)
void gate_gemm_kernel(const float* __restrict__ x,
                      const unsigned short* __restrict__ BF,
                      float* __restrict__ part) {
    constexpr int KBLK = DN / KSPLIT;   // k per block
    constexpr int NT   = KBLK / KC;     // chunks (16 for KSPLIT=2)

    // A[2 buf][2 plane][32][KPB]u16 = 34816 B; L[4][32][68]f32 = 34816 B alias
    __shared__ __align__(16) char smem[34816];
    typedef unsigned short AType[2][BM][KPB];
    AType* A = reinterpret_cast<AType*>(smem);
    typedef float LType[BM][68];
    LType* L = reinterpret_cast<LType*>(smem);

    const int tid  = threadIdx.x;
    const int lane = tid & 63;
    const int kq   = tid >> 6;          // wave id = K32 slot 0..3
    const int rt   = blockIdx.x >> 1;
    const int ks   = blockIdx.x & (KSPLIT - 1);
    const int r0   = rt * BM;
    const int k0   = ks * KBLK;
    const int s0   = k0 / 32;

    // staging: 8 threads/row, 16 contiguous floats (64B) each
    const int srow = tid >> 3;          // 0..31
    const int skf  = (tid & 7) * 16;    // float offset within chunk
    const float* xp = x + (size_t)(r0 + srow) * DN + k0 + skf;

    const int fr  = lane & 15;          // fragment row/col
    const int fko = (lane >> 4) * 8;    // fragment k offset within K=32
    const int kloc = kq * 32 + fko;

    f32x4 acc[2][4] = {};               // [row-half][expert-tile]

    float4 X0[4], X1[4];                // ping-pong x prefetch (depth 2)
    bf16x8 B0[8], B1[8];                // ping-pong B prefetch ([et]=hi, [4+et]=lo)

    auto loadX = [&](float4 (&X)[4], int t) {
        const float* p = xp + (size_t)t * KC;
        X[0] = *reinterpret_cast<const float4*>(p);
        X[1] = *reinterpret_cast<const float4*>(p + 4);
        X[2] = *reinterpret_cast<const float4*>(p + 8);
        X[3] = *reinterpret_cast<const float4*>(p + 12);
    };
    auto loadB = [&](bf16x8 (&B)[8], int t) {
        const int s = s0 + t * 4 + kq;
        const unsigned short* bp = BF + (size_t)s * 2048 + (size_t)lane * 8;
#pragma unroll
        for (int et = 0; et < 4; ++et)
            B[et] = *reinterpret_cast<const bf16x8*>(bp + et * 512);
#pragma unroll
        for (int et = 0; et < 4; ++et)
            B[4 + et] = *reinterpret_cast<const bf16x8*>(bp + (size_t)NS * 2048 + et * 512);
    };
    auto stage = [&](int b, float4 (&X)[4]) {
        float f[16] = {X[0].x, X[0].y, X[0].z, X[0].w,
                       X[1].x, X[1].y, X[1].z, X[1].w,
                       X[2].x, X[2].y, X[2].z, X[2].w,
                       X[3].x, X[3].y, X[3].z, X[3].w};
        bf16x8 vh[2], vl[2];
#pragma unroll
        for (int j = 0; j < 16; ++j) {
            unsigned short hh = f2bf(f[j]);
            vh[j >> 3][j & 7] = (short)hh;
            vl[j >> 3][j & 7] = (short)f2bf(f[j] - bf2f(hh));
        }
        *reinterpret_cast<bf16x8*>(&A[b][0][srow][skf])     = vh[0];
        *reinterpret_cast<bf16x8*>(&A[b][0][srow][skf + 8]) = vh[1];
        *reinterpret_cast<bf16x8*>(&A[b][1][srow][skf])     = vl[0];
        *reinterpret_cast<bf16x8*>(&A[b][1][srow][skf + 8]) = vl[1];
    };
    auto compute = [&](int b, bf16x8 (&B)[8]) {
        bf16x8 ah[2], al[2];
#pragma unroll
        for (int rh = 0; rh < 2; ++rh) {
            ah[rh] = *reinterpret_cast<const bf16x8*>(&A[b][0][rh * 16 + fr][kloc]);
            al[rh] = *reinterpret_cast<const bf16x8*>(&A[b][1][rh * 16 + fr][kloc]);
        }
#pragma unroll
        for (int et = 0; et < 4; ++et)
#pragma unroll
            for (int rh = 0; rh < 2; ++rh) {
                acc[rh][et] = __builtin_amdgcn_mfma_f32_16x16x32_bf16(ah[rh], B[et],     acc[rh][et], 0, 0, 0);
                acc[rh][et] = __builtin_amdgcn_mfma_f32_16x16x32_bf16(al[rh], B[et],     acc[rh][et], 0, 0, 0);
                acc[rh][et] = __builtin_amdgcn_mfma_f32_16x16x32_bf16(ah[rh], B[4 + et], acc[rh][et], 0, 0, 0);
                acc[rh][et] = __builtin_amdgcn_mfma_f32_16x16x32_bf16(al[rh], B[4 + et], acc[rh][et], 0, 0, 0);
            }
    };
    // body(t): issue B(t+1) FIRST, compute(t), stage(t+1), refill x(t+3)
    auto body = [&](int t, bf16x8 (&Bc)[8], bf16x8 (&Bn)[8],
                    float4 (&Xc)[4], int bc, int bn) {
        if (t + 1 < NT) loadB(Bn, t + 1);
        asm volatile("" ::: "memory");     // pin issue order
        compute(bc, Bc);
        if (t + 1 < NT) stage(bn, Xc);     // waits x(t+1): issued 2 iters ago
        if (t + 3 < NT) loadX(Xc, t + 3);  // refill consumed set
        asm volatile("" ::: "memory");
        __syncthreads();
    };

    // prologue: B(0); buf0 <- chunk0; X0 <- chunk1; X1 <- chunk2
    loadB(B0, 0);
    loadX(X0, 0);
    stage(0, X0);
    loadX(X0, 1);
    loadX(X1, 2);
    __syncthreads();

    for (int t = 0; t < NT; t += 2) {      // NT even; static ping-pong (rule #20)
        body(t,     B0, B1, X0, 0, 1);
        body(t + 1, B1, B0, X1, 1, 0);
    }

    // cross-wave k-slot reduction via LDS (alias A; body's last barrier protects)
#pragma unroll
    for (int rh = 0; rh < 2; ++rh)
#pragma unroll
        for (int et = 0; et < 4; ++et)
#pragma unroll
            for (int r = 0; r < 4; ++r)
                // C/D layout: col = lane&15, row = (lane>>4)*4 + reg  [m89]
                L[kq][rh * 16 + (lane >> 4) * 4 + r][et * 16 + fr] = acc[rh][et][r];
    __syncthreads();

    {
        const int row = tid >> 3;       // 0..31
        const int eg  = tid & 7;        // 8 experts each
        float v[8];
#pragma unroll
        for (int j = 0; j < 8; ++j)
            v[j] = L[0][row][eg * 8 + j] + L[1][row][eg * 8 + j]
                 + L[2][row][eg * 8 + j] + L[3][row][eg * 8 + j];
        float* dst = part + ((size_t)ks * TN + r0 + row) * EN + eg * 8;
        *reinterpret_cast<float4*>(dst)     = make_float4(v[0], v[1], v[2], v[3]);
        *reinterpret_cast<float4*>(dst + 4) = make_float4(v[4], v[5], v[6], v[7]);
    }
}

// Kernel 2: sum KSPLIT partials, top-1 softmax per row.
// out[0..TN) = argmax index (as float), out[TN..2TN) = max gate = 1/sumexp.
template <int NSPLIT>
__global__ __launch_bounds__(256)
void top1_softmax_kernel(const float* __restrict__ part, float* __restrict__ out) {
    const int row = blockIdx.x * blockDim.x + threadIdx.x;
    if (row >= TN) return;

    float v[EN];
#pragma unroll
    for (int i = 0; i < EN / 4; ++i) {
        float4 s = *reinterpret_cast<const float4*>(&part[(size_t)row * EN + i * 4]);
#pragma unroll
        for (int h = 1; h < NSPLIT; ++h) {
            float4 t = *reinterpret_cast<const float4*>(
                &part[((size_t)h * TN + row) * EN + i * 4]);
            s.x += t.x; s.y += t.y; s.z += t.z; s.w += t.w;
        }
        v[i * 4 + 0] = s.x; v[i * 4 + 1] = s.y;
        v[i * 4 + 2] = s.z; v[i * 4 + 3] = s.w;
    }

    float m = v[0];
    int idx = 0;
#pragma unroll
    for (int e = 1; e < EN; ++e)
        if (v[e] > m) { m = v[e]; idx = e; }  // strict >: first occurrence = jnp.argmax
    float s = 0.0f;
#pragma unroll
    for (int e = 0; e < EN; ++e) s += __expf(v[e] - m);

    out[row]      = (float)idx;
    out[TN + row] = 1.0f / s;
}

extern "C" void kernel_launch(void* const* d_in, const int* in_sizes, int n_in,
                              void* d_out, int out_size, void* d_ws, size_t ws_size,
                              hipStream_t stream) {
    const float* x  = (const float*)d_in[0];
    const float* wg = (const float*)d_in[1];
    float* out = (float*)d_out;

    constexpr size_t BF_BYTES = (size_t)2 * NS * 4 * 512 * 2;  // 1 MB
    unsigned short* BF = (unsigned short*)d_ws;
    float* part = (float*)((char*)d_ws + BF_BYTES);

    wg_frag_kernel<<<dim3(256), dim3(256), 0, stream>>>(wg, BF);

    const size_t need2 = BF_BYTES + (size_t)2 * TN * EN * sizeof(float);  // 5 MB
    if (ws_size >= need2) {
        gate_gemm_kernel<2><<<dim3(512), dim3(256), 0, stream>>>(x, BF, part);
        top1_softmax_kernel<2><<<dim3(TN / 256), dim3(256), 0, stream>>>(part, out);
    } else {
        gate_gemm_kernel<1><<<dim3(256), dim3(256), 0, stream>>>(x, BF, part);
        top1_softmax_kernel<1><<<dim3(TN / 256), dim3(256), 0, stream>>>(part, out);
    }
}

// Round 8
// 48.070 us; speedup vs baseline: 1.1385x; 1.1385x over previous
//
#include <hip/hip_runtime.h>

typedef __attribute__((ext_vector_type(8))) short bf16x8;
typedef __attribute__((ext_vector_type(4))) float f32x4;

constexpr int TN = 8192;   // tokens
constexpr int DN = 4096;   // model dim
constexpr int EN = 64;     // experts

constexpr int BM  = 16;        // rows per block
constexpr int KC  = 128;       // k per staged chunk (4 K32 slots = 4 waves)
constexpr int NT  = DN / KC;   // 32 chunks
constexpr int NS  = DN / 32;   // 128 MFMA k-steps total
constexpr int KPB = KC + 8;    // A k-stride bf16 (272B row: odd 16B-quad stride -> uniform banks)

__device__ __forceinline__ unsigned short f2bf(float f) {  // RNE f32->bf16
    unsigned u = __builtin_bit_cast(unsigned, f);
    u += 0x7FFFu + ((u >> 16) & 1u);
    return (unsigned short)(u >> 16);
}
__device__ __forceinline__ float bf2f(unsigned short h) {
    unsigned u = ((unsigned)h) << 16;
    return __builtin_bit_cast(float, u);
}

// Kernel 0: split wg into hi/lo bf16 planes in MFMA-fragment order:
// BF[p][s][et][lane*8+j] = plane_p( wg[et*16+(lane&15)][s*32+(lane>>4)*8+j] )
// so a wave's B-fragment load in the GEMM is base + lane*16B (1KB coalesced).
__global__ __launch_bounds__(256)
void wg_frag_kernel(const float* __restrict__ wg, unsigned short* __restrict__ BF) {
    const int gid = blockIdx.x * 256 + threadIdx.x;  // 65536 items
    const int l  = gid & 63;
    const int et = (gid >> 6) & 3;
    const int s  = (gid >> 8) & (NS - 1);
    const int p  = gid >> 15;
    const int e  = et * 16 + (l & 15);
    const int k  = s * 32 + (l >> 4) * 8;

    const float* src = wg + (size_t)e * DN + k;
    float4 v0 = *reinterpret_cast<const float4*>(src);
    float4 v1 = *reinterpret_cast<const float4*>(src + 4);
    float f[8] = {v0.x, v0.y, v0.z, v0.w, v1.x, v1.y, v1.z, v1.w};
    unsigned short o[8];
#pragma unroll
    for (int j = 0; j < 8; ++j) {
        unsigned short h = f2bf(f[j]);
        o[j] = p ? f2bf(f[j] - bf2f(h)) : h;
    }
    unsigned short* dst = BF + (((size_t)p * NS + s) * 4 + et) * 512 + (size_t)l * 8;
    *reinterpret_cast<ushort4*>(dst)     = make_ushort4(o[0], o[1], o[2], o[3]);
    *reinterpret_cast<ushort4*>(dst + 4) = make_ushort4(o[4], o[5], o[6], o[7]);
}

// Kernel 1: fused split-bf16 MFMA GEMM + top-1 softmax.
// Grid = 512 (2 blocks/CU), 256 threads = 4 waves; wave = K32 slot within
// each 128-wide chunk. Depth-2 register x-prefetch + B-register prefetch
// issued FIRST each iter. In-loop barrier is RAW s_barrier + lgkmcnt(0)
// only (ds_write visibility) -- never vmcnt(0): register-destined global
// prefetches stay in flight across the barrier (the R6 version's
// __syncthreads() forced a vmcnt(0) drain = full HBM latency per iter).
__global__ __launch_bounds__(256, 2)
void gate_fused_kernel(const float* __restrict__ x,
                       const unsigned short* __restrict__ BF,
                       float* __restrict__ out) {
    // A[2 buf][2 plane][16][KPB]u16 = 17408 B; L[4][16][68]f32 = 17408 B alias
    __shared__ __align__(16) char smem[17408];
    typedef unsigned short AType[2][BM][KPB];
    AType* A = reinterpret_cast<AType*>(smem);
    typedef float LType[BM][68];
    LType* L = reinterpret_cast<LType*>(smem);

    const int tid  = threadIdx.x;
    const int lane = tid & 63;
    const int kq   = tid >> 6;          // wave id = K32 slot 0..3
    const int r0   = blockIdx.x * BM;

    // staging: 16 threads/row, 8 contiguous floats (32B) each
    const int srow = tid >> 4;          // 0..15
    const int skf  = (tid & 15) * 8;    // float offset within chunk
    const float* xp = x + (size_t)(r0 + srow) * DN + skf;

    const int fr  = lane & 15;          // fragment row/col
    const int fko = (lane >> 4) * 8;    // fragment k offset within K=32
    const int kloc = kq * 32 + fko;

    f32x4 acc[4] = {};

    float4 X0[2], X1[2];                // ping-pong x prefetch (depth 2)
    bf16x8 B0[8], B1[8];                // ping-pong B prefetch ([et]=hi, [4+et]=lo)

    auto loadX = [&](float4 (&X)[2], int t) {
        const float* p = xp + (size_t)t * KC;
        X[0] = *reinterpret_cast<const float4*>(p);
        X[1] = *reinterpret_cast<const float4*>(p + 4);
    };
    auto loadB = [&](bf16x8 (&B)[8], int t) {
        const int s = t * 4 + kq;
        const unsigned short* bp = BF + (size_t)s * 2048 + (size_t)lane * 8;
#pragma unroll
        for (int et = 0; et < 4; ++et)
            B[et] = *reinterpret_cast<const bf16x8*>(bp + et * 512);
#pragma unroll
        for (int et = 0; et < 4; ++et)
            B[4 + et] = *reinterpret_cast<const bf16x8*>(bp + (size_t)NS * 2048 + et * 512);
    };
    auto stage = [&](int b, float4 (&X)[2]) {
        float f[8] = {X[0].x, X[0].y, X[0].z, X[0].w,
                      X[1].x, X[1].y, X[1].z, X[1].w};
        bf16x8 vh, vl;
#pragma unroll
        for (int j = 0; j < 8; ++j) {
            unsigned short hh = f2bf(f[j]);
            vh[j] = (short)hh;
            vl[j] = (short)f2bf(f[j] - bf2f(hh));
        }
        *reinterpret_cast<bf16x8*>(&A[b][0][srow][skf]) = vh;
        *reinterpret_cast<bf16x8*>(&A[b][1][srow][skf]) = vl;
    };
    auto compute = [&](int b, bf16x8 (&B)[8]) {
        bf16x8 ah = *reinterpret_cast<const bf16x8*>(&A[b][0][fr][kloc]);
        bf16x8 al = *reinterpret_cast<const bf16x8*>(&A[b][1][fr][kloc]);
#pragma unroll
        for (int et = 0; et < 4; ++et) {
            acc[et] = __builtin_amdgcn_mfma_f32_16x16x32_bf16(ah, B[et],     acc[et], 0, 0, 0);
            acc[et] = __builtin_amdgcn_mfma_f32_16x16x32_bf16(al, B[et],     acc[et], 0, 0, 0);
            acc[et] = __builtin_amdgcn_mfma_f32_16x16x32_bf16(ah, B[4 + et], acc[et], 0, 0, 0);
            acc[et] = __builtin_amdgcn_mfma_f32_16x16x32_bf16(al, B[4 + et], acc[et], 0, 0, 0);
        }
    };
    // non-draining barrier: ds_writes visible (lgkmcnt 0), global prefetch
    // stays in flight (no vmcnt drain). "memory" pins LDS op order.
    auto bar = [&]() {
        asm volatile("s_waitcnt lgkmcnt(0)" ::: "memory");
        __builtin_amdgcn_s_barrier();
        asm volatile("" ::: "memory");
    };
    // iteration body: issue B(t+1) FIRST, then compute(t), stage(t+1), refill x(t+3)
    auto body = [&](int t, bf16x8 (&Bc)[8], bf16x8 (&Bn)[8],
                    float4 (&Xc)[2], int bc, int bn) {
        if (t + 1 < NT) loadB(Bn, t + 1);
        asm volatile("" ::: "memory");     // pin issue order: B before compute's waits
        compute(bc, Bc);
        if (t + 1 < NT) stage(bn, Xc);     // vmcnt-waits x(t+1): issued 2 iters ago
        if (t + 3 < NT) loadX(Xc, t + 3);  // refill consumed set
        bar();
    };

    // prologue: B(0); buf0 <- chunk0; X0 <- chunk1; X1 <- chunk2
    loadB(B0, 0);
    loadX(X0, 0);
    stage(0, X0);
    loadX(X0, 1);
    loadX(X1, 2);
    __syncthreads();

    for (int t = 0; t < NT; t += 2) {      // NT even; static ping-pong (rule #20)
        body(t,     B0, B1, X0, 0, 1);
        body(t + 1, B1, B0, X1, 1, 0);
    }

    // epilogue: per-slot partial logits into LDS (alias A; loop's final
    // barrier already drained all ds_reads via lgkmcnt(0)), fused top-1 softmax
#pragma unroll
    for (int et = 0; et < 4; ++et)
#pragma unroll
        for (int r = 0; r < 4; ++r)
            // C/D layout: col = lane&15, row = (lane>>4)*4 + reg  [m89]
            L[kq][(lane >> 4) * 4 + r][et * 16 + fr] = acc[et][r];
    __syncthreads();

    {
        const int row = tid >> 4;   // 0..15
        const int eg  = tid & 15;   // 4 experts each
        float v[4];
#pragma unroll
        for (int j = 0; j < 4; ++j) {
            float s = L[0][row][eg * 4 + j];
#pragma unroll
            for (int q = 1; q < 4; ++q) s += L[q][row][eg * 4 + j];
            v[j] = s;
        }
        float m = v[0];
        int idx = eg * 4;
#pragma unroll
        for (int j = 1; j < 4; ++j)
            if (v[j] > m) { m = v[j]; idx = eg * 4 + j; }  // strict >: first occurrence
#pragma unroll
        for (int d = 1; d < 16; d <<= 1) {
            float om = __shfl_xor(m, d);
            int   oi = __shfl_xor(idx, d);
            if (om > m || (om == m && oi < idx)) { m = om; idx = oi; }
        }
        float s = 0.0f;
#pragma unroll
        for (int j = 0; j < 4; ++j) s += __expf(v[j] - m);
#pragma unroll
        for (int d = 1; d < 16; d <<= 1) s += __shfl_xor(s, d);
        if (eg == 0) {
            out[r0 + row]      = (float)idx;     // argmax index
            out[TN + r0 + row] = 1.0f / s;       // max gate = 1/sum(exp(l-lmax))
        }
    }
}

extern "C" void kernel_launch(void* const* d_in, const int* in_sizes, int n_in,
                              void* d_out, int out_size, void* d_ws, size_t ws_size,
                              hipStream_t stream) {
    const float* x  = (const float*)d_in[0];
    const float* wg = (const float*)d_in[1];
    float* out = (float*)d_out;

    unsigned short* BF = (unsigned short*)d_ws;  // 1 MB fragment-ordered hi/lo

    wg_frag_kernel<<<dim3(256), dim3(256), 0, stream>>>(wg, BF);
    gate_fused_kernel<<<dim3(TN / BM), dim3(256), 0, stream>>>(x, BF, out);
}

// Round 9
// 38.263 us; speedup vs baseline: 1.4302x; 1.2563x over previous
//
#include <hip/hip_runtime.h>

typedef __attribute__((ext_vector_type(8))) short bf16x8;
typedef __attribute__((ext_vector_type(4))) float f32x4;

constexpr int TN = 8192;   // tokens
constexpr int DN = 4096;   // model dim
constexpr int EN = 64;     // experts

constexpr int BM = 32;         // rows per block
constexpr int NS = DN / 32;    // 128 MFMA K32 slots
constexpr int NT = 16;         // slots per wave (128 / 8 waves)

__device__ __forceinline__ unsigned short f2bf(float f) {  // RNE f32->bf16
    unsigned u = __builtin_bit_cast(unsigned, f);
    u += 0x7FFFu + ((u >> 16) & 1u);
    return (unsigned short)(u >> 16);
}
__device__ __forceinline__ float bf2f(unsigned short h) {
    unsigned u = ((unsigned)h) << 16;
    return __builtin_bit_cast(float, u);
}

// Kernel 0: split wg into hi/lo bf16 planes in MFMA-fragment order:
// BF[p][s][et][lane*8+j] = plane_p( wg[et*16+(lane&15)][s*32+(lane>>4)*8+j] )
// so a wave's B-fragment load in the GEMM is base + lane*16B (1KB coalesced).
__global__ __launch_bounds__(256)
void wg_frag_kernel(const float* __restrict__ wg, unsigned short* __restrict__ BF) {
    const int gid = blockIdx.x * 256 + threadIdx.x;  // 65536 items
    const int l  = gid & 63;
    const int et = (gid >> 6) & 3;
    const int s  = (gid >> 8) & (NS - 1);
    const int p  = gid >> 15;
    const int e  = et * 16 + (l & 15);
    const int k  = s * 32 + (l >> 4) * 8;

    const float* src = wg + (size_t)e * DN + k;
    float4 v0 = *reinterpret_cast<const float4*>(src);
    float4 v1 = *reinterpret_cast<const float4*>(src + 4);
    float f[8] = {v0.x, v0.y, v0.z, v0.w, v1.x, v1.y, v1.z, v1.w};
    unsigned short o[8];
#pragma unroll
    for (int j = 0; j < 8; ++j) {
        unsigned short h = f2bf(f[j]);
        o[j] = p ? f2bf(f[j] - bf2f(h)) : h;
    }
    unsigned short* dst = BF + (((size_t)p * NS + s) * 4 + et) * 512 + (size_t)l * 8;
    *reinterpret_cast<ushort4*>(dst)     = make_ushort4(o[0], o[1], o[2], o[3]);
    *reinterpret_cast<ushort4*>(dst + 4) = make_ushort4(o[4], o[5], o[6], o[7]);
}

// Kernel 1: barrier-free direct-gather split-bf16 MFMA GEMM + fused top-1.
// Grid = 256 blocks (1/CU), 512 threads = 8 INDEPENDENT waves (no in-loop
// __syncthreads). Wave w = (kq=w&3, kh=w>>2) owns K32 slots kh*64+t*4+kq,
// t=0..15, and computes both 16-row halves of the block's 32 rows (B regs
// shared across rows). A-fragments are loaded per-lane straight from global
// x (lanes fr,fr+16,fr+32,fr+48 jointly cover one 128B line of row fr) and
// split to hi/lo bf16 in-register. Depth-2 ping-pong on A and B.
__global__ __launch_bounds__(512, 2)
void gate_fused_kernel(const float* __restrict__ x,
                       const unsigned short* __restrict__ BF,
                       float* __restrict__ out) {
    __shared__ float L[8][BM][68];      // 69632 B; per-wave partial logits

    const int tid  = threadIdx.x;
    const int lane = tid & 63;
    const int w    = tid >> 6;          // wave 0..7
    const int kq   = w & 3;
    const int kh   = w >> 2;
    const int r0   = blockIdx.x * BM;

    const int fr  = lane & 15;          // fragment row (A) / expert col (B)
    const int fko = (lane >> 4) * 8;    // fragment k offset within K=32

    // per-lane A base: row r0+fr, +rh*16 rows, + s*32 + fko floats
    const float* xa = x + (size_t)(r0 + fr) * DN + fko;

    f32x4 acc[2][4] = {};               // [row-half][expert-tile]

    float4 XA0[2][2], XA1[2][2];        // ping-pong A fp32 ([rh][2x dwordx4])
    bf16x8 B0[8], B1[8];                // ping-pong B ([et]=hi, [4+et]=lo)

    auto loadA = [&](float4 (&XA)[2][2], int t) {
        const int s = kh * 64 + t * 4 + kq;
        const float* p = xa + s * 32;
#pragma unroll
        for (int rh = 0; rh < 2; ++rh) {
            const float* pr = p + (size_t)rh * 16 * DN;
            XA[rh][0] = *reinterpret_cast<const float4*>(pr);
            XA[rh][1] = *reinterpret_cast<const float4*>(pr + 4);
        }
    };
    auto loadB = [&](bf16x8 (&B)[8], int t) {
        const int s = kh * 64 + t * 4 + kq;
        const unsigned short* bp = BF + (size_t)s * 2048 + (size_t)lane * 8;
#pragma unroll
        for (int et = 0; et < 4; ++et)
            B[et] = *reinterpret_cast<const bf16x8*>(bp + et * 512);
#pragma unroll
        for (int et = 0; et < 4; ++et)
            B[4 + et] = *reinterpret_cast<const bf16x8*>(bp + (size_t)NS * 2048 + et * 512);
    };
    auto compute = [&](float4 (&XA)[2][2], bf16x8 (&B)[8]) {
        bf16x8 ah[2], al[2];
#pragma unroll
        for (int rh = 0; rh < 2; ++rh) {
            float f[8] = {XA[rh][0].x, XA[rh][0].y, XA[rh][0].z, XA[rh][0].w,
                          XA[rh][1].x, XA[rh][1].y, XA[rh][1].z, XA[rh][1].w};
#pragma unroll
            for (int j = 0; j < 8; ++j) {
                unsigned short hh = f2bf(f[j]);
                ah[rh][j] = (short)hh;
                al[rh][j] = (short)f2bf(f[j] - bf2f(hh));
            }
        }
#pragma unroll
        for (int et = 0; et < 4; ++et)
#pragma unroll
            for (int rh = 0; rh < 2; ++rh) {
                acc[rh][et] = __builtin_amdgcn_mfma_f32_16x16x32_bf16(ah[rh], B[et],     acc[rh][et], 0, 0, 0);
                acc[rh][et] = __builtin_amdgcn_mfma_f32_16x16x32_bf16(al[rh], B[et],     acc[rh][et], 0, 0, 0);
                acc[rh][et] = __builtin_amdgcn_mfma_f32_16x16x32_bf16(ah[rh], B[4 + et], acc[rh][et], 0, 0, 0);
                acc[rh][et] = __builtin_amdgcn_mfma_f32_16x16x32_bf16(al[rh], B[4 + et], acc[rh][et], 0, 0, 0);
            }
    };

    // barrier-free ping-pong pipeline: every load has >=1.5 iters of slack
    loadA(XA0, 0);
    loadB(B0, 0);
#pragma unroll 2
    for (int t = 0; t < NT; t += 2) {   // NT=16 even; static ping-pong (rule #20)
        if (t + 1 < NT) { loadA(XA1, t + 1); loadB(B1, t + 1); }
        compute(XA0, B0);
        if (t + 2 < NT) { loadA(XA0, t + 2); loadB(B0, t + 2); }
        compute(XA1, B1);
    }

    // epilogue: per-wave partial logits to LDS, then fused top-1 softmax
#pragma unroll
    for (int rh = 0; rh < 2; ++rh)
#pragma unroll
        for (int et = 0; et < 4; ++et)
#pragma unroll
            for (int r = 0; r < 4; ++r)
                // C/D layout: col = lane&15, row = (lane>>4)*4 + reg  [m89]
                L[w][rh * 16 + (lane >> 4) * 4 + r][et * 16 + fr] = acc[rh][et][r];
    __syncthreads();

    {
        const int row = tid >> 4;       // 0..31
        const int eg  = tid & 15;       // 4 experts each
        float v[4];
#pragma unroll
        for (int j = 0; j < 4; ++j) {
            float s = L[0][row][eg * 4 + j];
#pragma unroll
            for (int q = 1; q < 8; ++q) s += L[q][row][eg * 4 + j];
            v[j] = s;
        }
        float m = v[0];
        int idx = eg * 4;
#pragma unroll
        for (int j = 1; j < 4; ++j)
            if (v[j] > m) { m = v[j]; idx = eg * 4 + j; }  // strict >: first occurrence
#pragma unroll
        for (int d = 1; d < 16; d <<= 1) {
            float om = __shfl_xor(m, d);
            int   oi = __shfl_xor(idx, d);
            if (om > m || (om == m && oi < idx)) { m = om; idx = oi; }
        }
        float s = 0.0f;
#pragma unroll
        for (int j = 0; j < 4; ++j) s += __expf(v[j] - m);
#pragma unroll
        for (int d = 1; d < 16; d <<= 1) s += __shfl_xor(s, d);
        if (eg == 0) {
            out[r0 + row]      = (float)idx;     // argmax index
            out[TN + r0 + row] = 1.0f / s;       // max gate = 1/sum(exp(l-lmax))
        }
    }
}

extern "C" void kernel_launch(void* const* d_in, const int* in_sizes, int n_in,
                              void* d_out, int out_size, void* d_ws, size_t ws_size,
                              hipStream_t stream) {
    const float* x  = (const float*)d_in[0];
    const float* wg = (const float*)d_in[1];
    float* out = (float*)d_out;

    unsigned short* BF = (unsigned short*)d_ws;  // 1 MB fragment-ordered hi/lo

    wg_frag_kernel<<<dim3(256), dim3(256), 0, stream>>>(wg, BF);
    gate_fused_kernel<<<dim3(TN / BM), dim3(512), 0, stream>>>(x, BF, out);
}